// Round 2
// baseline (302.434 us; speedup 1.0000x reference)
//
#include <hip/hip_runtime.h>
#include <cstdint>
#include <cstddef>

typedef unsigned long long u64;

// ---------------- problem constants ----------------
constexpr int Bn   = 8;
constexpr int Pn   = 2000;
constexpr int Cn   = 81;
constexpr int CM1  = 80;
constexpr int KPRE = 2048;
constexpr int NDET = 100;
constexpr int SECP = 8;              // proposals per K1 block
constexpr int NSEC2 = Pn / SECP;     // 250 sections per image
constexpr int CAP  = 4096;           // post-threshold cap (sort buffer)
constexpr int ACAP = 38400;          // raw candidate cap/img (max 2000*19=38000)
constexpr int NBINS = 5632;          // score-bits histogram bins
constexpr int BINOFF = (122 << 10);  // exponent 122 (scores > 0.05 > 2^-5)
constexpr float W_IMG = 1333.0f;
constexpr float H_IMG = 800.0f;
constexpr float XFORM_CLIP = 4.135166556742356f; // log(1000/16)
constexpr float NMS_OFF = 1334.0f;               // max(W,H)+1

// ---------------- ws layout (bytes) ----------------
constexpr size_t OFF_HIST = 0;                          // Bn*NBINS int (memset 0)
constexpr size_t OFF_GCNT = (size_t)Bn * NBINS * 4;     // Bn int      (memset 0)
constexpr size_t ZERO_BYTES = OFF_GCNT + (size_t)Bn * 4;
constexpr size_t OFF_CALL = ZERO_BYTES;                 // Bn*ACAP u64 (8B aligned)

__device__ __forceinline__ void decode_clip(const float4 rv, float w, float h,
                                            float cx, float cy, float out[4]) {
  float dx = rv.x / 10.0f;
  float dy = rv.y / 10.0f;
  float dw = fminf(rv.z / 5.0f, XFORM_CLIP);
  float dh = fminf(rv.w / 5.0f, XFORM_CLIP);
  float pcx = dx * w + cx;
  float pcy = dy * h + cy;
  float pw = expf(dw) * w;
  float ph = expf(dh) * h;
  out[0] = fminf(fmaxf(pcx - 0.5f * pw, 0.0f), W_IMG);
  out[1] = fminf(fmaxf(pcy - 0.5f * ph, 0.0f), H_IMG);
  out[2] = fminf(fmaxf(pcx + 0.5f * pw, 0.0f), W_IMG);
  out[3] = fminf(fmaxf(pcy + 0.5f * ph, 0.0f), H_IMG);
}

__device__ __forceinline__ int score_bin(unsigned bits) {
  int bin = (int)(bits >> 13) - BINOFF;
  return min(max(bin, 0), NBINS - 1);
}

// decode a candidate key into raw clipped box + label + score
__device__ __forceinline__ void key_decode(u64 key, int b,
                                           const float* __restrict__ reg,
                                           const float* __restrict__ props,
                                           float bx[4], int& label, float& sc) {
  sc = __uint_as_float((unsigned)(key >> 32));
  bx[0] = bx[1] = bx[2] = bx[3] = 0.0f;
  label = 0;
  if (key != 0ull) {
    int m = (int)(0xFFFFFFFFu - (unsigned)key);
    int p = m / CM1;
    int c = m - p * CM1 + 1;
    int nidx = b * Pn + p;
    const float4 pb = *reinterpret_cast<const float4*>(props + (size_t)nidx * 4);
    float w = pb.z - pb.x, h = pb.w - pb.y;
    float cx = pb.x + 0.5f * w, cy = pb.y + 0.5f * h;
    float4 rv = *reinterpret_cast<const float4*>(reg + (size_t)nidx * (Cn * 4) + c * 4);
    decode_clip(rv, w, h, cx, cy, bx);
    label = c;
  }
}

// ---------------- K1: softmax + decode + valid -> dense append + histogram ---
__global__ __launch_bounds__(256) void
k1_score(const float* __restrict__ logits, const float* __restrict__ reg,
         const float* __restrict__ props, u64* __restrict__ candAll,
         int* __restrict__ gcnt, int* __restrict__ hist) {
  int blk = blockIdx.x, t = threadIdx.x, lane = t & 63, wv = t >> 6;
  int b = blk / NSEC2, sec = blk % NSEC2;
  int* hrow = hist + (size_t)b * NBINS;
  u64* crow = candAll + (size_t)b * ACAP;

  #pragma unroll
  for (int pp = wv; pp < SECP; pp += 4) {
    int p = sec * SECP + pp;
    int wid = b * Pn + p;
    const float* lg = logits + (size_t)wid * Cn;
    float x0 = lg[lane];
    float x1 = (lane < Cn - 64) ? lg[64 + lane] : -3.4e38f;
    float mx = fmaxf(x0, x1);
    for (int m = 32; m; m >>= 1) mx = fmaxf(mx, __shfl_xor(mx, m, 64));
    float e0 = expf(x0 - mx);
    float e1 = (lane < Cn - 64) ? expf(x1 - mx) : 0.0f;
    float ssum = e0 + e1;
    for (int m = 32; m; m >>= 1) ssum += __shfl_xor(ssum, m, 64);

    const float4 pb = *reinterpret_cast<const float4*>(props + (size_t)wid * 4);
    float w = pb.z - pb.x, h = pb.w - pb.y;
    float cx = pb.x + 0.5f * w, cy = pb.y + 0.5f * h;
    const float* rrow = reg + (size_t)wid * (Cn * 4);

    u64 key0 = 0ull, key1 = 0ull;
    if (lane >= 1) {                     // class c = lane (1..63)
      float sc = e0 / ssum;
      if (sc > 0.05f) {
        float4 rv = *reinterpret_cast<const float4*>(rrow + lane * 4);
        float bx[4];
        decode_clip(rv, w, h, cx, cy, bx);
        if ((bx[2] - bx[0] >= 0.01f) && (bx[3] - bx[1] >= 0.01f)) {
          unsigned m = (unsigned)(p * CM1 + (lane - 1));
          key0 = ((u64)__float_as_uint(sc) << 32) | (0xFFFFFFFFu - m);
        }
      }
    }
    if (lane < Cn - 64) {                // class c = 64+lane (64..80)
      int c = 64 + lane;
      float sc = e1 / ssum;
      if (sc > 0.05f) {
        float4 rv = *reinterpret_cast<const float4*>(rrow + c * 4);
        float bx[4];
        decode_clip(rv, w, h, cx, cy, bx);
        if ((bx[2] - bx[0] >= 0.01f) && (bx[3] - bx[1] >= 0.01f)) {
          unsigned m = (unsigned)(p * CM1 + (c - 1));
          key1 = ((u64)__float_as_uint(sc) << 32) | (0xFFFFFFFFu - m);
        }
      }
    }
    u64 bal0 = __ballot(key0 != 0ull);
    u64 bal1 = __ballot(key1 != 0ull);
    int tot = __popcll(bal0) + __popcll(bal1);
    if (tot) {
      int base = 0;
      if (lane == 0) base = atomicAdd(&gcnt[b], tot);   // dense per-image append
      base = __shfl(base, 0, 64);
      int r0 = __popcll(bal0 & ((1ull << lane) - 1ull));
      int r1 = __popcll(bal0) + __popcll(bal1 & ((1ull << lane) - 1ull));
      if (key0) {
        crow[base + r0] = key0;
        atomicAdd(&hrow[score_bin((unsigned)(key0 >> 32))], 1);
      }
      if (key1) {
        crow[base + r1] = key1;
        atomicAdd(&hrow[score_bin((unsigned)(key1 >> 32))], 1);
      }
    }
  }
}

// in-place reg-staged merge-path round over LDS (desc, A-priority, exact)
// used only for the final 4096 -> top-2048 truncating merge
template <int CHV>
__device__ __forceinline__ void mp_round(u64* buf, int base, int nA, int nB,
                                         int outLen, int tid) {
  const u64* A = buf + base;
  const u64* B = buf + base + nA;
  int d = tid * CHV;
  u64 rg[CHV];
  int cnt = 0;
  if (d < outLen) {
    int lo = max(0, d - nB), hi = min(d, nA);
    while (lo < hi) {
      int mid = (lo + hi) >> 1;
      if (A[mid] >= B[d - 1 - mid]) lo = mid + 1; else hi = mid;
    }
    int i = lo, j = d - lo;
    for (int e = 0; e < CHV && d + e < outLen; e++) {
      u64 v;
      if (j >= nB || (i < nA && A[i] >= B[j])) v = A[i++];
      else v = B[j++];
      rg[cnt++] = v;
    }
  }
  __syncthreads();
  for (int e = 0; e < cnt; e++) buf[base + d + e] = rg[e];
  __syncthreads();
}

// generic merge round: pairs of sorted len/2 runs -> sorted len runs, in place.
// segments entirely past `cnt` are all-zero and skipped (barriers stay uniform).
template <int CHV>
__device__ __forceinline__ void mp_seg_round(u64* buf, int len, int cnt, int t) {
  int tps = len / CHV;           // threads per segment (CAP/CHV == 1024 total)
  int seg = t / tps;
  int tid = t - seg * tps;
  int base = seg * len;
  bool act = (base < cnt);
  int nA = len >> 1;
  int d = tid * CHV;
  u64 rg[CHV];
  if (act) {
    const u64* A = buf + base;
    const u64* B = buf + base + nA;
    int lo = max(0, d - nA), hi = min(d, nA);
    while (lo < hi) {
      int mid = (lo + hi) >> 1;
      if (A[mid] >= B[d - 1 - mid]) lo = mid + 1; else hi = mid;
    }
    int i = lo, j = d - lo;
    #pragma unroll
    for (int e = 0; e < CHV; e++) {
      u64 v;
      if (j >= nA || (i < nA && A[i] >= B[j])) v = A[i++];
      else v = B[j++];
      rg[e] = v;
    }
  }
  __syncthreads();
  if (act) {
    #pragma unroll
    for (int e = 0; e < CHV; e++) buf[base + d + e] = rg[e];
  }
  __syncthreads();
}

// ---------------- K2: threshold + compact + reg-sort + merge + NMS ----------
__global__ __launch_bounds__(1024) void
k2_fused(const int* __restrict__ hist, const u64* __restrict__ candAll,
         const int* __restrict__ gcnt, const float* __restrict__ reg,
         const float* __restrict__ props, float* __restrict__ out) {
  int b = blockIdx.x, t = threadIdx.x, lane = t & 63, w = t >> 6;  // 16 waves
  __shared__ u64 bufA[CAP];            // 32 KB: keys (compact/sort/merge) then obox
  __shared__ u64 keys2[KPRE];          // 16 KB: merged keys live here for output
  __shared__ u64 maskb[256][4];        // 8 KB
  __shared__ u64 keepw[KPRE / 64];     // 256 B
  __shared__ int accI[NDET];
  __shared__ int hlds[NBINS];          // 22.5 KB: LDS-cached histogram
  __shared__ int sufAfter[256];
  __shared__ int chunkTot[4];
  __shared__ int tmax_sh, cnt_sh, kcnt_sh;
  float4* obox = (float4*)bufA;

  // ---- phase 0: coalesced hist -> LDS, zero sort buffer ----
  const int* hrow = hist + (size_t)b * NBINS;
  if (t == 0) { tmax_sh = 0; cnt_sh = 0; }
  for (int i = t; i < NBINS; i += 1024) hlds[i] = hrow[i];
  for (int i = t; i < CAP; i += 1024) bufA[i] = 0ull;
  __syncthreads();

  // ---- phase A: suffix counts -> score-bin threshold T (2-barrier scan) ----
  const int CH = NBINS / 256;  // 22
  int suf = 0;
  if (t < 256) {               // waves 0..3 entirely
    int lo = t * CH;
    int s = 0;
    #pragma unroll
    for (int i = 0; i < CH; i++) s += hlds[lo + i];
    // in-wave inclusive suffix scan (Hillis-Steele via shfl_down, no barriers)
    for (int d2 = 1; d2 < 64; d2 <<= 1) {
      int v = __shfl_down(s, d2, 64);
      if (lane + d2 < 64) s += v;
    }
    if (lane == 0) chunkTot[t >> 6] = s;   // lane0 holds whole-chunk total
    suf = s;
  }
  __syncthreads();
  if (t < 256) {
    int w4 = t >> 6;
    for (int q = w4 + 1; q < 4; q++) suf += chunkTot[q];
    sufAfter[t] = suf;                     // = sum of partials [t..255]
  }
  __syncthreads();
  if (t < 256) {
    int lo = t * CH, hi = lo + CH;
    int cum = (t + 1 < 256) ? sufAfter[t + 1] : 0;  // suffix AFTER this range
    int cand = -1;
    for (int i = hi - 1; i >= lo; i--) {
      cum += hlds[i];
      if (cum >= KPRE) { cand = i; break; }
    }
    if (cand >= 0) atomicMax(&tmax_sh, cand);
  }
  __syncthreads();
  int T = tmax_sh;

  // ---- phase B: filter dense candidate array -> compact into LDS ----
  int n = min(gcnt[b], ACAP);
  const u64* crow = candAll + (size_t)b * ACAP;
  {
    int i0 = t & ~63;                      // wave-uniform base; i = i0 + lane
    u64 nxt = (i0 + lane < n) ? crow[i0 + lane] : 0ull;   // prefetch
    for (; i0 < n; i0 += 1024) {
      u64 key = nxt;
      int j0 = i0 + 1024;
      nxt = (j0 + lane < n) ? crow[j0 + lane] : 0ull;     // next iter in flight
      bool pass = key && (score_bin((unsigned)(key >> 32)) >= T);
      u64 bal = __ballot(pass);
      int tot = __popcll(bal);
      if (tot) {
        int base = 0;
        if (lane == 0) base = atomicAdd(&cnt_sh, tot);
        base = __shfl(base, 0, 64);
        int rank = __popcll(bal & ((1ull << lane) - 1ull));
        int pos = base + rank;
        if (pass && pos < CAP) bufA[pos] = key;
      }
    }
  }
  __syncthreads();
  int cnt = min(cnt_sh, CAP);

  // ---- phase C: 64-wide register bitonic sorts (desc), zero barriers ----
  for (int r = w; (r << 6) < cnt; r += 16) {
    u64 v = bufA[(r << 6) | lane];
    #pragma unroll
    for (int k = 2; k <= 64; k <<= 1) {
      #pragma unroll
      for (int j = k >> 1; j > 0; j >>= 1) {
        u64 o = __shfl_xor(v, j, 64);
        bool dir = ((lane & k) == 0);      // descending block
        bool lower = ((lane & j) == 0);
        u64 mn = (v < o) ? v : o;
        u64 mx = (v < o) ? o : v;
        v = (dir == lower) ? mx : mn;
      }
    }
    bufA[(r << 6) | lane] = v;
  }
  __syncthreads();

  // ---- phase D: merge tree 64 -> 4096, then truncate to top-2048 ----
  mp_seg_round<4>(bufA, 128, cnt, t);
  mp_seg_round<4>(bufA, 256, cnt, t);
  mp_seg_round<4>(bufA, 512, cnt, t);
  mp_seg_round<4>(bufA, 1024, cnt, t);
  mp_seg_round<4>(bufA, 2048, cnt, t);
  if (cnt > 2048)
    mp_round<2>(bufA, 0, 2048, 2048, 2048, t);   // exact truncation

  // ---- keep merged keys in LDS, init keepw, decode obox (aliases bufA) ----
  u64 k0 = bufA[t], k1v = bufA[t + 1024];
  keys2[t] = k0;
  keys2[t + 1024] = k1v;
  {
    u64 bal = __ballot(k0 != 0ull);
    if (lane == 0) keepw[w] = bal;
    bal = __ballot(k1v != 0ull);
    if (lane == 0) keepw[16 + w] = bal;
  }
  __syncthreads();
  #pragma unroll
  for (int s = 0; s < 2; s++) {
    int j = t + s * 1024;
    u64 key = s ? k1v : k0;
    float bx[4]; int label; float sc;
    key_decode(key, b, reg, props, bx, label, sc);
    float off = (float)label * NMS_OFF;
    obox[j] = make_float4(bx[0] + off, bx[1] + off, bx[2] + off, bx[3] + off);
  }
  __syncthreads();

  // ---- windowed bitmask greedy NMS with early exit ----
  int kcount = 0;
  for (int w0 = 0; w0 < KPRE && kcount < NDET; w0 += 256) {
    // step1: suppress window cols by previously accepted boxes
    if (w0 > 0 && kcount > 0) {
      if (t < 256) {
        int j = w0 + t;
        u64 kwv = keepw[j >> 6];
        bool alive = (kwv >> (j & 63)) & 1ull;
        if (alive) {
          float4 jb = obox[j];
          float jar = fmaxf(jb.z - jb.x, 0.0f) * fmaxf(jb.w - jb.y, 0.0f);
          for (int a = 0; a < kcount; a++) {
            float4 ab = obox[accI[a]];
            float ix1 = fmaxf(ab.x, jb.x), iy1 = fmaxf(ab.y, jb.y);
            float ix2 = fminf(ab.z, jb.z), iy2 = fminf(ab.w, jb.w);
            float iw = fmaxf(ix2 - ix1, 0.0f), ih = fmaxf(iy2 - iy1, 0.0f);
            float inter = iw * ih;
            if (inter > 0.0f) {
              float aar = fmaxf(ab.z - ab.x, 0.0f) * fmaxf(ab.w - ab.y, 0.0f);
              float iou = inter / fmaxf(aar + jar - inter, 1e-9f);
              if (iou > 0.5f) { alive = false; break; }
            }
          }
        }
        u64 bal = __ballot(alive);
        if (lane == 0) keepw[(w0 >> 6) + (t >> 6)] = bal;
      }
      __syncthreads();
    }
    // step2: window-internal suppression bitmask (row r = t>>2, word wd = t&3)
    {
      int r = t >> 2, wd = t & 3;
      int rgp = w0 + r;
      bool ralive = (keepw[rgp >> 6] >> (rgp & 63)) & 1ull;
      float4 rb = obox[rgp];
      float rar = fmaxf(rb.z - rb.x, 0.0f) * fmaxf(rb.w - rb.y, 0.0f);
      u64 m = 0;
      if (ralive) {
        int cb0 = w0 + wd * 64;
        for (int jj = 0; jj < 64; jj++) {
          int cg = cb0 + jj;
          float4 cb = obox[cg];
          float ix1 = fmaxf(rb.x, cb.x), iy1 = fmaxf(rb.y, cb.y);
          float ix2 = fminf(rb.z, cb.z), iy2 = fminf(rb.w, cb.w);
          float iw = fmaxf(ix2 - ix1, 0.0f), ih = fmaxf(iy2 - iy1, 0.0f);
          float inter = iw * ih;
          if (inter > 0.0f && cg > rgp) {
            float car = fmaxf(cb.z - cb.x, 0.0f) * fmaxf(cb.w - cb.y, 0.0f);
            float iou = inter / fmaxf(rar + car - inter, 1e-9f);
            if (iou > 0.5f) m |= (1ull << jj);
          }
        }
      }
      maskb[r][wd] = m;
    }
    __syncthreads();
    // step3: single-wave serial greedy reduce over the window
    if (w == 0) {
      u64 kw0 = keepw[(w0 >> 6) + 0];
      u64 kw1 = keepw[(w0 >> 6) + 1];
      u64 kw2 = keepw[(w0 >> 6) + 2];
      u64 kw3 = keepw[(w0 >> 6) + 3];
      int kc = kcount;
      #pragma unroll
      for (int wq = 0; wq < 4; wq++) {
        u64 cw = (wq == 0) ? kw0 : (wq == 1) ? kw1 : (wq == 2) ? kw2 : kw3;
        if (cw == 0ull) continue;
        for (int rb0 = 0; rb0 < 64 && kc < NDET; rb0 += 4) {
          u64 gbits = (cw >> rb0) & 0xFull;
          int r = wq * 64 + rb0;
          u64 rm0a = maskb[r][0],   rm0b = maskb[r][1],   rm0c = maskb[r][2],   rm0d = maskb[r][3];
          u64 rm1a = maskb[r+1][0], rm1b = maskb[r+1][1], rm1c = maskb[r+1][2], rm1d = maskb[r+1][3];
          u64 rm2a = maskb[r+2][0], rm2b = maskb[r+2][1], rm2c = maskb[r+2][2], rm2d = maskb[r+2][3];
          u64 rm3a = maskb[r+3][0], rm3b = maskb[r+3][1], rm3c = maskb[r+3][2], rm3d = maskb[r+3][3];
          if (gbits == 0ull) continue;
          #pragma unroll
          for (int d = 0; d < 4; d++) {
            u64 cwq = (wq == 0) ? kw0 : (wq == 1) ? kw1 : (wq == 2) ? kw2 : kw3;
            if ((cwq >> (rb0 + d)) & 1ull) {
              if (lane == 0) accI[kc] = w0 + r + d;
              kc++;
              if (kc >= NDET) break;
              u64 ma = (d == 0) ? rm0a : (d == 1) ? rm1a : (d == 2) ? rm2a : rm3a;
              u64 mb = (d == 0) ? rm0b : (d == 1) ? rm1b : (d == 2) ? rm2b : rm3b;
              u64 mc = (d == 0) ? rm0c : (d == 1) ? rm1c : (d == 2) ? rm2c : rm3c;
              u64 md = (d == 0) ? rm0d : (d == 1) ? rm1d : (d == 2) ? rm2d : rm3d;
              kw0 &= ~ma; kw1 &= ~mb; kw2 &= ~mc; kw3 &= ~md;
            }
          }
          cw = (wq == 0) ? kw0 : (wq == 1) ? kw1 : (wq == 2) ? kw2 : kw3;
        }
      }
      if (lane == 0) {
        keepw[(w0 >> 6) + 0] = kw0;
        keepw[(w0 >> 6) + 1] = kw1;
        keepw[(w0 >> 6) + 2] = kw2;
        keepw[(w0 >> 6) + 3] = kw3;
        kcnt_sh = kc;
      }
    }
    __syncthreads();
    kcount = kcnt_sh;
  }

  // rare path: fewer than 100 kept -> backfill non-kept ascending
  if (t == 0 && kcount < NDET) {
    int run = kcount;
    for (int wq = 0; wq < KPRE / 64 && run < NDET; wq++) {
      u64 nk = ~keepw[wq];
      while (nk && run < NDET) {
        int bit2 = __ffsll((long long)nk) - 1;
        nk &= nk - 1;
        accI[run++] = wq * 64 + bit2;
      }
    }
  }
  __syncthreads();

  if (t < NDET) {
    int k = accI[t];
    bool kept = t < kcount;
    u64 key = keys2[k];                    // merged keys kept in LDS
    float bx[4]; int label; float sc;
    key_decode(key, b, reg, props, bx, label, sc);
    int oi = b * NDET + t;
    out[(size_t)oi * 4 + 0] = bx[0];
    out[(size_t)oi * 4 + 1] = bx[1];
    out[(size_t)oi * 4 + 2] = bx[2];
    out[(size_t)oi * 4 + 3] = bx[3];
    out[Bn * NDET * 4 + oi] = kept ? sc : -1.0f;
    out[Bn * NDET * 5 + oi] = (float)label;
    out[Bn * NDET * 6 + oi] = kept ? 1.0f : 0.0f;
  }
}

extern "C" void kernel_launch(void* const* d_in, const int* in_sizes, int n_in,
                              void* d_out, int out_size, void* d_ws, size_t ws_size,
                              hipStream_t stream) {
  const float* logits = (const float*)d_in[0];
  const float* reg    = (const float*)d_in[1];
  const float* props  = (const float*)d_in[2];
  float* out = (float*)d_out;
  char* ws = (char*)d_ws;

  int* hist    = (int*)(ws + OFF_HIST);
  int* gcnt    = (int*)(ws + OFF_GCNT);
  u64* candAll = (u64*)(ws + OFF_CALL);

  hipMemsetAsync(ws + OFF_HIST, 0, ZERO_BYTES, stream);
  k1_score<<<Bn * NSEC2, 256, 0, stream>>>(logits, reg, props, candAll, gcnt, hist);
  k2_fused<<<Bn, 1024, 0, stream>>>(hist, candAll, gcnt, reg, props, out);
}

// Round 4
// 135.604 us; speedup vs baseline: 2.2303x; 2.2303x over previous
//
#include <hip/hip_runtime.h>
#include <cstdint>
#include <cstddef>

typedef unsigned long long u64;

// ---------------- problem constants ----------------
constexpr int Bn   = 8;
constexpr int Pn   = 2000;
constexpr int Cn   = 81;
constexpr int CM1  = 80;
constexpr int KPRE = 2048;
constexpr int NDET = 100;
constexpr int SECP = 8;              // proposals per K1 block
constexpr int NSEC2 = Pn / SECP;     // 250 sections per image
constexpr int SSLOT = 160;           // slice stride (hard max 8*19 = 152)
constexpr int CAP  = 4096;           // sort buffer / post-threshold cap
constexpr int NBINS = 5632;          // score-bits histogram bins
constexpr int BINOFF = (122 << 10);  // exponent 122 (scores > 0.05 > 2^-5)
constexpr float W_IMG = 1333.0f;
constexpr float H_IMG = 800.0f;
constexpr float XFORM_CLIP = 4.135166556742356f; // log(1000/16)
constexpr float NMS_OFF = 1334.0f;               // max(W,H)+1

// ---------------- ws layout (bytes) ---- no zero-init needed anywhere ------
constexpr size_t OFF_SL = 0;                                  // Bn*NSEC2*SSLOT u64
constexpr size_t OFF_SC = (size_t)Bn * NSEC2 * SSLOT * 8;     // Bn*NSEC2 int

__device__ __forceinline__ void decode_clip(const float4 rv, float w, float h,
                                            float cx, float cy, float out[4]) {
  float dx = rv.x / 10.0f;
  float dy = rv.y / 10.0f;
  float dw = fminf(rv.z / 5.0f, XFORM_CLIP);
  float dh = fminf(rv.w / 5.0f, XFORM_CLIP);
  float pcx = dx * w + cx;
  float pcy = dy * h + cy;
  float pw = expf(dw) * w;
  float ph = expf(dh) * h;
  out[0] = fminf(fmaxf(pcx - 0.5f * pw, 0.0f), W_IMG);
  out[1] = fminf(fmaxf(pcy - 0.5f * ph, 0.0f), H_IMG);
  out[2] = fminf(fmaxf(pcx + 0.5f * pw, 0.0f), W_IMG);
  out[3] = fminf(fmaxf(pcy + 0.5f * ph, 0.0f), H_IMG);
}

__device__ __forceinline__ int score_bin(unsigned bits) {
  int bin = (int)(bits >> 13) - BINOFF;
  return min(max(bin, 0), NBINS - 1);
}

// decode a candidate key into raw clipped box + label + score
__device__ __forceinline__ void key_decode(u64 key, int b,
                                           const float* __restrict__ reg,
                                           const float* __restrict__ props,
                                           float bx[4], int& label, float& sc) {
  sc = __uint_as_float((unsigned)(key >> 32));
  bx[0] = bx[1] = bx[2] = bx[3] = 0.0f;
  label = 0;
  if (key != 0ull) {
    int m = (int)(0xFFFFFFFFu - (unsigned)key);
    int p = m / CM1;
    int c = m - p * CM1 + 1;
    int nidx = b * Pn + p;
    const float4 pb = *reinterpret_cast<const float4*>(props + (size_t)nidx * 4);
    float w = pb.z - pb.x, h = pb.w - pb.y;
    float cx = pb.x + 0.5f * w, cy = pb.y + 0.5f * h;
    float4 rv = *reinterpret_cast<const float4*>(reg + (size_t)nidx * (Cn * 4) + c * 4);
    decode_clip(rv, w, h, cx, cy, bx);
    label = c;
  }
}

// ---------------- K1: softmax + decode + valid -> per-section slices --------
// (no global atomics at all: block-local LDS compaction, coalesced writes)
__global__ __launch_bounds__(256) void
k1_score(const float* __restrict__ logits, const float* __restrict__ reg,
         const float* __restrict__ props, u64* __restrict__ slices,
         int* __restrict__ scnt) {
  int blk = blockIdx.x, t = threadIdx.x, lane = t & 63, wv = t >> 6;
  int b = blk / NSEC2, sec = blk % NSEC2;
  __shared__ u64 cbuf[SSLOT];
  __shared__ int cnt_sh;
  if (t == 0) cnt_sh = 0;
  __syncthreads();

  #pragma unroll
  for (int pp = wv; pp < SECP; pp += 4) {
    int p = sec * SECP + pp;
    int wid = b * Pn + p;
    const float* lg = logits + (size_t)wid * Cn;
    float x0 = lg[lane];
    float x1 = (lane < Cn - 64) ? lg[64 + lane] : -3.4e38f;
    float mx = fmaxf(x0, x1);
    for (int m = 32; m; m >>= 1) mx = fmaxf(mx, __shfl_xor(mx, m, 64));
    float e0 = expf(x0 - mx);
    float e1 = (lane < Cn - 64) ? expf(x1 - mx) : 0.0f;
    float ssum = e0 + e1;
    for (int m = 32; m; m >>= 1) ssum += __shfl_xor(ssum, m, 64);

    const float4 pb = *reinterpret_cast<const float4*>(props + (size_t)wid * 4);
    float w = pb.z - pb.x, h = pb.w - pb.y;
    float cx = pb.x + 0.5f * w, cy = pb.y + 0.5f * h;
    const float* rrow = reg + (size_t)wid * (Cn * 4);

    u64 key0 = 0ull, key1 = 0ull;
    if (lane >= 1) {                     // class c = lane (1..63)
      float sc = e0 / ssum;
      if (sc > 0.05f) {
        float4 rv = *reinterpret_cast<const float4*>(rrow + lane * 4);
        float bx[4];
        decode_clip(rv, w, h, cx, cy, bx);
        if ((bx[2] - bx[0] >= 0.01f) && (bx[3] - bx[1] >= 0.01f)) {
          unsigned m = (unsigned)(p * CM1 + (lane - 1));
          key0 = ((u64)__float_as_uint(sc) << 32) | (0xFFFFFFFFu - m);
        }
      }
    }
    if (lane < Cn - 64) {                // class c = 64+lane (64..80)
      int c = 64 + lane;
      float sc = e1 / ssum;
      if (sc > 0.05f) {
        float4 rv = *reinterpret_cast<const float4*>(rrow + c * 4);
        float bx[4];
        decode_clip(rv, w, h, cx, cy, bx);
        if ((bx[2] - bx[0] >= 0.01f) && (bx[3] - bx[1] >= 0.01f)) {
          unsigned m = (unsigned)(p * CM1 + (c - 1));
          key1 = ((u64)__float_as_uint(sc) << 32) | (0xFFFFFFFFu - m);
        }
      }
    }
    u64 bal0 = __ballot(key0 != 0ull);
    u64 bal1 = __ballot(key1 != 0ull);
    int tot = __popcll(bal0) + __popcll(bal1);
    if (tot) {
      int base = 0;
      if (lane == 0) base = atomicAdd(&cnt_sh, tot);   // LDS atomic only
      base = __shfl(base, 0, 64);
      int r0 = __popcll(bal0 & ((1ull << lane) - 1ull));
      int r1 = __popcll(bal0) + __popcll(bal1 & ((1ull << lane) - 1ull));
      if (key0) cbuf[base + r0] = key0;
      if (key1) cbuf[base + r1] = key1;
    }
  }
  __syncthreads();
  int n = cnt_sh;                         // <= 152
  for (int i = t; i < n; i += 256) slices[(size_t)blk * SSLOT + i] = cbuf[i];
  if (t == 0) scnt[blk] = n;
}

// in-place reg-staged merge-path round over LDS (desc, A-priority, exact)
// used only for the final 4096 -> top-2048 truncating merge
template <int CHV>
__device__ __forceinline__ void mp_round(u64* buf, int base, int nA, int nB,
                                         int outLen, int tid) {
  const u64* A = buf + base;
  const u64* B = buf + base + nA;
  int d = tid * CHV;
  u64 rg[CHV];
  int cnt = 0;
  if (d < outLen) {
    int lo = max(0, d - nB), hi = min(d, nA);
    while (lo < hi) {
      int mid = (lo + hi) >> 1;
      if (A[mid] >= B[d - 1 - mid]) lo = mid + 1; else hi = mid;
    }
    int i = lo, j = d - lo;
    for (int e = 0; e < CHV && d + e < outLen; e++) {
      u64 v;
      if (j >= nB || (i < nA && A[i] >= B[j])) v = A[i++];
      else v = B[j++];
      rg[cnt++] = v;
    }
  }
  __syncthreads();
  for (int e = 0; e < cnt; e++) buf[base + d + e] = rg[e];
  __syncthreads();
}

// generic merge round: pairs of sorted len/2 runs -> sorted len runs, in place.
// segments entirely past `cnt` are all-zero and skipped (barriers stay uniform).
template <int CHV>
__device__ __forceinline__ void mp_seg_round(u64* buf, int len, int cnt, int t) {
  int tps = len / CHV;           // threads per segment (CAP/CHV == 1024 total)
  int seg = t / tps;
  int tid = t - seg * tps;
  int base = seg * len;
  bool act = (base < cnt);
  int nA = len >> 1;
  int d = tid * CHV;
  u64 rg[CHV];
  if (act) {
    const u64* A = buf + base;
    const u64* B = buf + base + nA;
    int lo = max(0, d - nA), hi = min(d, nA);
    while (lo < hi) {
      int mid = (lo + hi) >> 1;
      if (A[mid] >= B[d - 1 - mid]) lo = mid + 1; else hi = mid;
    }
    int i = lo, j = d - lo;
    #pragma unroll
    for (int e = 0; e < CHV; e++) {
      u64 v;
      if (j >= nA || (i < nA && A[i] >= B[j])) v = A[i++];
      else v = B[j++];
      rg[e] = v;
    }
  }
  __syncthreads();
  if (act) {
    #pragma unroll
    for (int e = 0; e < CHV; e++) buf[base + d + e] = rg[e];
  }
  __syncthreads();
}

// ---------------- K2: stream+hist+cache -> (threshold) -> sort -> NMS -------
__global__ __launch_bounds__(1024) void
k2_fused(const u64* __restrict__ slices, const int* __restrict__ scnt,
         const float* __restrict__ reg, const float* __restrict__ props,
         float* __restrict__ out) {
  int b = blockIdx.x, t = threadIdx.x, lane = t & 63, w = t >> 6;  // 16 waves
  __shared__ u64 bufA[CAP];            // 32 KB: keys (cache/sort/merge) then obox
  __shared__ u64 keys2[KPRE];          // 16 KB: merged keys live here for output
  __shared__ u64 maskb[256][4];        // 8 KB
  __shared__ u64 keepw[KPRE / 64];     // 256 B
  __shared__ int accI[NDET];
  __shared__ int hlds[NBINS];          // 22.5 KB: LDS histogram
  __shared__ int lcnt[NSEC2];
  __shared__ int sufAfter[256];
  __shared__ int chunkTot[4];
  __shared__ int tmax_sh, cnt_sh, kcnt_sh;
  float4* obox = (float4*)bufA;

  // ---- init: zero hist + sort buffer, load per-section counts ----
  for (int i = t; i < NBINS; i += 1024) hlds[i] = 0;
  for (int i = t; i < CAP; i += 1024) bufA[i] = 0ull;
  if (t < NSEC2) lcnt[t] = scnt[b * NSEC2 + t];
  if (t == 0) { tmax_sh = 0; cnt_sh = 0; }
  __syncthreads();

  // ---- pass 1: stream slices -> LDS hist + opportunistic cache into bufA ---
  for (int sec = w; sec < NSEC2; sec += 16) {
    int n = lcnt[sec];
    const u64* sl = slices + (size_t)(b * NSEC2 + sec) * SSLOT;
    for (int i0 = 0; i0 < n; i0 += 64) {
      int i = i0 + lane;
      u64 key = (i < n) ? sl[i] : 0ull;
      bool has = key != 0ull;
      u64 bal = __ballot(has);
      int tot = __popcll(bal);
      if (tot) {
        int base = 0;
        if (lane == 0) base = atomicAdd(&cnt_sh, tot);
        base = __shfl(base, 0, 64);
        int rank = __popcll(bal & ((1ull << lane) - 1ull));
        int pos = base + rank;
        if (has) {
          if (pos < CAP) bufA[pos] = key;
          atomicAdd(&hlds[score_bin((unsigned)(key >> 32))], 1);
        }
      }
    }
  }
  __syncthreads();
  int rawcnt = cnt_sh;
  int cnt;
  if (rawcnt <= CAP) {
    cnt = rawcnt;                        // all candidates cached in LDS: no
                                         // threshold, no second pass needed
  } else {
    // ---- fallback A: suffix scan on hlds -> score-bin threshold T ----
    const int CH = NBINS / 256;  // 22
    int suf = 0;
    if (t < 256) {               // waves 0..3 entirely
      int lo = t * CH;
      int s = 0;
      #pragma unroll
      for (int i = 0; i < CH; i++) s += hlds[lo + i];
      for (int d2 = 1; d2 < 64; d2 <<= 1) {   // in-wave suffix scan
        int v = __shfl_down(s, d2, 64);
        if (lane + d2 < 64) s += v;
      }
      if (lane == 0) chunkTot[t >> 6] = s;
      suf = s;
    }
    __syncthreads();
    if (t < 256) {
      int w4 = t >> 6;
      for (int q = w4 + 1; q < 4; q++) suf += chunkTot[q];
      sufAfter[t] = suf;
    }
    __syncthreads();
    if (t < 256) {
      int lo = t * CH, hi = lo + CH;
      int cum = (t + 1 < 256) ? sufAfter[t + 1] : 0;
      int cand = -1;
      for (int i = hi - 1; i >= lo; i--) {
        cum += hlds[i];
        if (cum >= KPRE) { cand = i; break; }
      }
      if (cand >= 0) atomicMax(&tmax_sh, cand);
    }
    __syncthreads();
    int T = tmax_sh;
    // ---- fallback B: re-zero cache, filtered second pass over slices ----
    for (int i = t; i < CAP; i += 1024) bufA[i] = 0ull;
    if (t == 0) cnt_sh = 0;
    __syncthreads();
    for (int sec = w; sec < NSEC2; sec += 16) {
      int n = lcnt[sec];
      const u64* sl = slices + (size_t)(b * NSEC2 + sec) * SSLOT;
      for (int i0 = 0; i0 < n; i0 += 64) {
        int i = i0 + lane;
        u64 key = (i < n) ? sl[i] : 0ull;
        bool pass = key && (score_bin((unsigned)(key >> 32)) >= T);
        u64 bal = __ballot(pass);
        int tot = __popcll(bal);
        if (tot) {
          int base = 0;
          if (lane == 0) base = atomicAdd(&cnt_sh, tot);
          base = __shfl(base, 0, 64);
          int rank = __popcll(bal & ((1ull << lane) - 1ull));
          int pos = base + rank;
          if (pass && pos < CAP) bufA[pos] = key;
        }
      }
    }
    __syncthreads();
    cnt = min(cnt_sh, CAP);
  }

  // ---- phase C: 64-wide register bitonic sorts (desc), zero barriers ----
  for (int r = w; (r << 6) < cnt; r += 16) {
    u64 v = bufA[(r << 6) | lane];
    #pragma unroll
    for (int k = 2; k <= 64; k <<= 1) {
      #pragma unroll
      for (int j = k >> 1; j > 0; j >>= 1) {
        u64 o = __shfl_xor(v, j, 64);
        bool dir = ((lane & k) == 0);      // descending block
        bool lower = ((lane & j) == 0);
        u64 mn = (v < o) ? v : o;
        u64 mx = (v < o) ? o : v;
        v = (dir == lower) ? mx : mn;
      }
    }
    bufA[(r << 6) | lane] = v;
  }
  __syncthreads();

  // ---- phase D: merge tree 64 -> 4096, then truncate to top-2048 ----
  mp_seg_round<4>(bufA, 128, cnt, t);
  mp_seg_round<4>(bufA, 256, cnt, t);
  mp_seg_round<4>(bufA, 512, cnt, t);
  mp_seg_round<4>(bufA, 1024, cnt, t);
  mp_seg_round<4>(bufA, 2048, cnt, t);
  if (cnt > 2048)
    mp_round<2>(bufA, 0, 2048, 2048, 2048, t);   // exact truncation

  // ---- keep merged keys in LDS, init keepw, decode obox (aliases bufA) ----
  u64 k0 = bufA[t], k1v = bufA[t + 1024];
  keys2[t] = k0;
  keys2[t + 1024] = k1v;
  {
    u64 bal = __ballot(k0 != 0ull);
    if (lane == 0) keepw[w] = bal;
    bal = __ballot(k1v != 0ull);
    if (lane == 0) keepw[16 + w] = bal;
  }
  __syncthreads();
  #pragma unroll
  for (int s = 0; s < 2; s++) {
    int j = t + s * 1024;
    u64 key = s ? k1v : k0;
    float bx[4]; int label; float sc;
    key_decode(key, b, reg, props, bx, label, sc);
    float off = (float)label * NMS_OFF;
    obox[j] = make_float4(bx[0] + off, bx[1] + off, bx[2] + off, bx[3] + off);
  }
  __syncthreads();

  // ---- windowed bitmask greedy NMS with early exit ----
  int kcount = 0;
  for (int w0 = 0; w0 < KPRE && kcount < NDET; w0 += 256) {
    // step1: suppress window cols by previously accepted boxes
    if (w0 > 0 && kcount > 0) {
      if (t < 256) {
        int j = w0 + t;
        u64 kwv = keepw[j >> 6];
        bool alive = (kwv >> (j & 63)) & 1ull;
        if (alive) {
          float4 jb = obox[j];
          float jar = fmaxf(jb.z - jb.x, 0.0f) * fmaxf(jb.w - jb.y, 0.0f);
          for (int a = 0; a < kcount; a++) {
            float4 ab = obox[accI[a]];
            float ix1 = fmaxf(ab.x, jb.x), iy1 = fmaxf(ab.y, jb.y);
            float ix2 = fminf(ab.z, jb.z), iy2 = fminf(ab.w, jb.w);
            float iw = fmaxf(ix2 - ix1, 0.0f), ih = fmaxf(iy2 - iy1, 0.0f);
            float inter = iw * ih;
            if (inter > 0.0f) {
              float aar = fmaxf(ab.z - ab.x, 0.0f) * fmaxf(ab.w - ab.y, 0.0f);
              float iou = inter / fmaxf(aar + jar - inter, 1e-9f);
              if (iou > 0.5f) { alive = false; break; }
            }
          }
        }
        u64 bal = __ballot(alive);
        if (lane == 0) keepw[(w0 >> 6) + (t >> 6)] = bal;
      }
      __syncthreads();
    }
    // step2: window-internal suppression bitmask (row r = t>>2, word wd = t&3)
    {
      int r = t >> 2, wd = t & 3;
      int rgp = w0 + r;
      bool ralive = (keepw[rgp >> 6] >> (rgp & 63)) & 1ull;
      float4 rb = obox[rgp];
      float rar = fmaxf(rb.z - rb.x, 0.0f) * fmaxf(rb.w - rb.y, 0.0f);
      u64 m = 0;
      if (ralive) {
        int cb0 = w0 + wd * 64;
        for (int jj = 0; jj < 64; jj++) {
          int cg = cb0 + jj;
          float4 cb = obox[cg];
          float ix1 = fmaxf(rb.x, cb.x), iy1 = fmaxf(rb.y, cb.y);
          float ix2 = fminf(rb.z, cb.z), iy2 = fminf(rb.w, cb.w);
          float iw = fmaxf(ix2 - ix1, 0.0f), ih = fmaxf(iy2 - iy1, 0.0f);
          float inter = iw * ih;
          if (inter > 0.0f && cg > rgp) {
            float car = fmaxf(cb.z - cb.x, 0.0f) * fmaxf(cb.w - cb.y, 0.0f);
            float iou = inter / fmaxf(rar + car - inter, 1e-9f);
            if (iou > 0.5f) m |= (1ull << jj);
          }
        }
      }
      maskb[r][wd] = m;
    }
    __syncthreads();
    // step3: single-wave serial greedy reduce over the window
    if (w == 0) {
      u64 kw0 = keepw[(w0 >> 6) + 0];
      u64 kw1 = keepw[(w0 >> 6) + 1];
      u64 kw2 = keepw[(w0 >> 6) + 2];
      u64 kw3 = keepw[(w0 >> 6) + 3];
      int kc = kcount;
      #pragma unroll
      for (int wq = 0; wq < 4; wq++) {
        u64 cw = (wq == 0) ? kw0 : (wq == 1) ? kw1 : (wq == 2) ? kw2 : kw3;
        if (cw == 0ull) continue;
        for (int rb0 = 0; rb0 < 64 && kc < NDET; rb0 += 4) {
          u64 gbits = (cw >> rb0) & 0xFull;
          int r = wq * 64 + rb0;
          u64 rm0a = maskb[r][0],   rm0b = maskb[r][1],   rm0c = maskb[r][2],   rm0d = maskb[r][3];
          u64 rm1a = maskb[r+1][0], rm1b = maskb[r+1][1], rm1c = maskb[r+1][2], rm1d = maskb[r+1][3];
          u64 rm2a = maskb[r+2][0], rm2b = maskb[r+2][1], rm2c = maskb[r+2][2], rm2d = maskb[r+2][3];
          u64 rm3a = maskb[r+3][0], rm3b = maskb[r+3][1], rm3c = maskb[r+3][2], rm3d = maskb[r+3][3];
          if (gbits == 0ull) continue;
          #pragma unroll
          for (int d = 0; d < 4; d++) {
            u64 cwq = (wq == 0) ? kw0 : (wq == 1) ? kw1 : (wq == 2) ? kw2 : kw3;
            if ((cwq >> (rb0 + d)) & 1ull) {
              if (lane == 0) accI[kc] = w0 + r + d;
              kc++;
              if (kc >= NDET) break;
              u64 ma = (d == 0) ? rm0a : (d == 1) ? rm1a : (d == 2) ? rm2a : rm3a;
              u64 mb = (d == 0) ? rm0b : (d == 1) ? rm1b : (d == 2) ? rm2b : rm3b;
              u64 mc = (d == 0) ? rm0c : (d == 1) ? rm1c : (d == 2) ? rm2c : rm3c;
              u64 md = (d == 0) ? rm0d : (d == 1) ? rm1d : (d == 2) ? rm2d : rm3d;
              kw0 &= ~ma; kw1 &= ~mb; kw2 &= ~mc; kw3 &= ~md;
            }
          }
          cw = (wq == 0) ? kw0 : (wq == 1) ? kw1 : (wq == 2) ? kw2 : kw3;
        }
      }
      if (lane == 0) {
        keepw[(w0 >> 6) + 0] = kw0;
        keepw[(w0 >> 6) + 1] = kw1;
        keepw[(w0 >> 6) + 2] = kw2;
        keepw[(w0 >> 6) + 3] = kw3;
        kcnt_sh = kc;
      }
    }
    __syncthreads();
    kcount = kcnt_sh;
  }

  // rare path: fewer than 100 kept -> backfill non-kept ascending
  if (t == 0 && kcount < NDET) {
    int run = kcount;
    for (int wq = 0; wq < KPRE / 64 && run < NDET; wq++) {
      u64 nk = ~keepw[wq];
      while (nk && run < NDET) {
        int bit2 = __ffsll((long long)nk) - 1;
        nk &= nk - 1;
        accI[run++] = wq * 64 + bit2;
      }
    }
  }
  __syncthreads();

  if (t < NDET) {
    int k = accI[t];
    bool kept = t < kcount;
    u64 key = keys2[k];                    // merged keys kept in LDS
    float bx[4]; int label; float sc;
    key_decode(key, b, reg, props, bx, label, sc);
    int oi = b * NDET + t;
    out[(size_t)oi * 4 + 0] = bx[0];
    out[(size_t)oi * 4 + 1] = bx[1];
    out[(size_t)oi * 4 + 2] = bx[2];
    out[(size_t)oi * 4 + 3] = bx[3];
    out[Bn * NDET * 4 + oi] = kept ? sc : -1.0f;
    out[Bn * NDET * 5 + oi] = (float)label;
    out[Bn * NDET * 6 + oi] = kept ? 1.0f : 0.0f;
  }
}

extern "C" void kernel_launch(void* const* d_in, const int* in_sizes, int n_in,
                              void* d_out, int out_size, void* d_ws, size_t ws_size,
                              hipStream_t stream) {
  const float* logits = (const float*)d_in[0];
  const float* reg    = (const float*)d_in[1];
  const float* props  = (const float*)d_in[2];
  float* out = (float*)d_out;
  char* ws = (char*)d_ws;

  u64* slices = (u64*)(ws + OFF_SL);
  int* scnt   = (int*)(ws + OFF_SC);

  k1_score<<<Bn * NSEC2, 256, 0, stream>>>(logits, reg, props, slices, scnt);
  k2_fused<<<Bn, 1024, 0, stream>>>(slices, scnt, reg, props, out);
}